// Round 2
// baseline (26439.651 us; speedup 1.0000x reference)
//
#include <hip/hip_runtime.h>
#include <stdint.h>

typedef unsigned short u16;
typedef short v8s __attribute__((ext_vector_type(8)));
typedef float v4f __attribute__((ext_vector_type(4)));

#define B_ 64
#define S_ 1024
#define IN_ 256
#define H_ 512
#define OUT_ 256
#define BS_ (B_ * S_)                 // 65536
#define GS_ ((size_t)BS_ * H_)        // elems per gate buffer
#define NSLAB_ 16
#define NGRP_ 4

static __device__ __forceinline__ u16 f2bf(float f) {
  uint32_t u = __float_as_uint(f);
  u += 0x7FFFu + ((u >> 16) & 1u);   // round-to-nearest-even
  return (u16)(u >> 16);
}
static __device__ __forceinline__ float bf2f(u16 h) {
  return __uint_as_float(((uint32_t)h) << 16);
}
static __device__ __forceinline__ v4f mfma16(v8s a, v8s b, v4f c) {
  return __builtin_amdgcn_mfma_f32_16x16x32_bf16(a, b, c, 0, 0, 0);
}

// ---------------------------------------------------------------- utilities
__global__ void cast_input_kernel(const float* __restrict__ src,
                                  u16* __restrict__ dst, int n4) {
  int i = blockIdx.x * blockDim.x + threadIdx.x;
  int stride = gridDim.x * blockDim.x;
  for (; i < n4; i += stride) {
    float4 v = ((const float4*)src)[i];
    uint32_t lo = (uint32_t)f2bf(v.x) | ((uint32_t)f2bf(v.y) << 16);
    uint32_t hi = (uint32_t)f2bf(v.z) | ((uint32_t)f2bf(v.w) << 16);
    ((uint2*)dst)[i] = make_uint2(lo, hi);
  }
}

// dst[n*K + k] = bf16(src[k*N + n])   (transpose + cast)
__global__ void pack_transpose_kernel(const float* __restrict__ src,
                                      u16* __restrict__ dst, int K, int N) {
  int i = blockIdx.x * blockDim.x + threadIdx.x;
  int total = K * N;
  int stride = gridDim.x * blockDim.x;
  for (; i < total; i += stride) {
    int n = i / K, k = i - n * K;
    dst[i] = f2bf(src[(size_t)k * N + n]);
  }
}

__global__ void init_layer_kernel(const float* __restrict__ hs,
                                  u16* __restrict__ hbuf,
                                  float* __restrict__ hbuf32,
                                  int layer, int* __restrict__ flags) {
  int i = blockIdx.x * blockDim.x + threadIdx.x;
  if (i < B_ * H_) {
    int b = i >> 9, h = i & (H_ - 1);
    float v = hs[((size_t)b * 2 + layer) * H_ + h];
    hbuf[i] = f2bf(v);
    hbuf32[i] = v;
  }
  if (i < 16) flags[i] = 0;
}

// ---------------------------------------------------------------- GEMM
// C[M x N] = A[M x K] * Bt[N x K]^T ; 64x64 block tile, 4 waves of 32x32.
// mode 0: bf16 out split into 3 gate buffers of [BS_][H_] (N = 1536)
// mode 1: f32 out with bias (N = OUT_)
__global__ void __launch_bounds__(256) gemm_kernel(
    const u16* __restrict__ A, const u16* __restrict__ Bt, int N, int K,
    u16* __restrict__ outb, float* __restrict__ outf,
    const float* __restrict__ bias, int mode) {
  const int bn = blockIdx.x * 64;
  const int bm = blockIdx.y * 64;
  const int w = threadIdx.x >> 6;
  const int lane = threadIdx.x & 63;
  const int wm = (w >> 1) * 32, wn = (w & 1) * 32;
  const int fr = lane & 15;
  const int kb = (lane >> 4) * 8;
  v4f acc00 = {0,0,0,0}, acc01 = {0,0,0,0}, acc10 = {0,0,0,0}, acc11 = {0,0,0,0};
  const u16* a0p = A + (size_t)(bm + wm + fr) * K + kb;
  const u16* a1p = a0p + (size_t)16 * K;
  const u16* b0p = Bt + (size_t)(bn + wn + fr) * K + kb;
  const u16* b1p = b0p + (size_t)16 * K;
  for (int kk = 0; kk < K; kk += 32) {
    v8s a0 = *(const v8s*)(a0p + kk);
    v8s a1 = *(const v8s*)(a1p + kk);
    v8s b0 = *(const v8s*)(b0p + kk);
    v8s b1 = *(const v8s*)(b1p + kk);
    acc00 = mfma16(a0, b0, acc00);
    acc01 = mfma16(a0, b1, acc01);
    acc10 = mfma16(a1, b0, acc10);
    acc11 = mfma16(a1, b1, acc11);
  }
  v4f accs[2][2] = {{acc00, acc01}, {acc10, acc11}};
  const int rb = (lane >> 4) * 4;
#pragma unroll
  for (int mi = 0; mi < 2; ++mi)
#pragma unroll
    for (int ni = 0; ni < 2; ++ni)
#pragma unroll
      for (int j = 0; j < 4; ++j) {
        int row = bm + wm + mi * 16 + rb + j;
        int col = bn + wn + ni * 16 + fr;
        float v = accs[mi][ni][j];
        if (mode == 0) {
          int gate = col >> 9, c = col & (H_ - 1);
          outb[(size_t)gate * GS_ + (size_t)row * H_ + c] = f2bf(v);
        } else {
          outf[(size_t)row * N + col] = v + bias[col];
        }
      }
}

// ---------------------------------------------------------------- GRU scan
// 64 WGs = 4 batch-groups (16 rows) x 16 column-slabs (32 cols).
// Recurrent weight slabs live in LDS for all 1024 steps; h / hr exchanged
// through device memory with agent-scope flag barriers (2 per step).
// NOTE: xproj and seqout may alias (layer 1 writes h over the consumed
// z-projection slot of the same step) -> no __restrict__ on them.
__global__ void __launch_bounds__(256, 1) gru_scan_kernel(
    const u16* xproj,                // [3][BS_][H_] bf16 (z,r,g)
    const u16* __restrict__ Wht,     // [3][H_][H_] bf16, Wt[g][n][k] = W[k][n]
    const float* __restrict__ bz, const float* __restrict__ br,
    const float* __restrict__ bg,
    u16* __restrict__ hbuf, float* __restrict__ hbuf32,
    u16* __restrict__ hrbuf,
    u16* seqout,                     // [B_][S_][H_] bf16
    float* __restrict__ hfinal,      // [B_][H_] f32 (d_out tail slice)
    int* __restrict__ flags) {
  __shared__ __align__(16) u16 ldsW[3][32][H_ + 8];  // +8: bank-conflict pad
  const int grp = blockIdx.x & (NGRP_ - 1);
  const int slab = blockIdx.x >> 2;
  const int j0 = slab * 32;
  const int tid = threadIdx.x;

  // stage weight slabs (once)
  for (int idx = tid; idx < 3 * 32 * 64; idx += 256) {
    int gate = idx >> 11;
    int rem = idx & 2047;
    int cl = rem >> 6;
    int kc = (rem & 63) * 8;
    *(v8s*)&ldsW[gate][cl][kc] =
        *(const v8s*)(Wht + ((size_t)gate * H_ + (j0 + cl)) * H_ + kc);
  }
  __syncthreads();

  const int w = tid >> 6, lane = tid & 63;
  const int fr = lane & 15;
  const int kb = (lane >> 4) * 8;
  const int rb = (lane >> 4) * 4;
  const int gb = grp * 16;          // batch row base of this group
  const int nt = w & 1;             // N-tile within slab
  const int gateA = w >> 1;         // waves 0,1 -> z ; waves 2,3 -> r
  const int colL = nt * 16 + fr;
  const int gcol = j0 + colL;
  const float biasA = (gateA == 0) ? bz[gcol] : br[gcol];
  const float biasG = bg[gcol];
  int* flagA = flags + grp;
  int* flagB = flags + NGRP_ + grp;

  const u16* hrow  = hbuf  + (size_t)(gb + fr) * H_ + kb;
  const u16* hrrow = hrbuf + (size_t)(gb + fr) * H_ + kb;
  const u16* xA = xproj + (size_t)gateA * GS_;
  const u16* xG = xproj + (size_t)2 * GS_;
  const u16* wA = &ldsW[gateA][colL][kb];
  const u16* wG = &ldsW[2][colL][kb];

  float zv0 = 0.f, zv1 = 0.f, zv2 = 0.f, zv3 = 0.f;

  for (int t = 0; t < S_; ++t) {
    // ---------- phase A: z (waves 0,1) and r -> hr (waves 2,3) ----------
    v4f acc0 = {0,0,0,0}, acc1 = {0,0,0,0};   // two chains: K halves
#pragma unroll
    for (int kk = 0; kk < 8; ++kk) {
      v8s a0 = *(const v8s*)(hrow + kk * 32);
      v8s b0 = *(const v8s*)(wA + kk * 32);
      acc0 = mfma16(a0, b0, acc0);
      v8s a1 = *(const v8s*)(hrow + 256 + kk * 32);
      v8s b1 = *(const v8s*)(wA + 256 + kk * 32);
      acc1 = mfma16(a1, b1, acc1);
    }
    float pre[4];
#pragma unroll
    for (int j = 0; j < 4; ++j) {
      int b = gb + rb + j;
      float x = bf2f(xA[((size_t)b * S_ + t) * H_ + gcol]);
      float s = acc0[j] + acc1[j] + x + biasA;
      pre[j] = 1.0f / (1.0f + __expf(-s));
    }
    if (gateA == 0) {
      zv0 = pre[0]; zv1 = pre[1]; zv2 = pre[2]; zv3 = pre[3];
    } else {
#pragma unroll
      for (int j = 0; j < 4; ++j) {
        int b = gb + rb + j;
        float hold = hbuf32[(size_t)b * H_ + gcol];
        hrbuf[(size_t)b * H_ + gcol] = f2bf(pre[j] * hold);
      }
    }
    __syncthreads();
    if (tid == 0) {
      __threadfence();
      __hip_atomic_fetch_add(flagA, 1, __ATOMIC_RELEASE, __HIP_MEMORY_SCOPE_AGENT);
      const int target = NSLAB_ * (t + 1);
      while (__hip_atomic_load(flagA, __ATOMIC_ACQUIRE, __HIP_MEMORY_SCOPE_AGENT) < target)
        __builtin_amdgcn_s_sleep(2);
    }
    __syncthreads();

    // ---------- phase B: g (waves 0,1), h update ----------
    if (w < 2) {
      v4f g0 = {0,0,0,0}, g1 = {0,0,0,0};
#pragma unroll
      for (int kk = 0; kk < 8; ++kk) {
        v8s a0 = *(const v8s*)(hrrow + kk * 32);
        v8s b0 = *(const v8s*)(wG + kk * 32);
        g0 = mfma16(a0, b0, g0);
        v8s a1 = *(const v8s*)(hrrow + 256 + kk * 32);
        v8s b1 = *(const v8s*)(wG + 256 + kk * 32);
        g1 = mfma16(a1, b1, g1);
      }
      float zv[4] = {zv0, zv1, zv2, zv3};
#pragma unroll
      for (int j = 0; j < 4; ++j) {
        int b = gb + rb + j;
        float xg = bf2f(xG[((size_t)b * S_ + t) * H_ + gcol]);
        float gval = tanhf(g0[j] + g1[j] + xg + biasG);
        float hold = hbuf32[(size_t)b * H_ + gcol];
        float hnew = zv[j] * hold + (1.0f - zv[j]) * gval;
        u16 hb = f2bf(hnew);
        hbuf32[(size_t)b * H_ + gcol] = hnew;
        hbuf[(size_t)b * H_ + gcol] = hb;
        seqout[((size_t)b * S_ + t) * H_ + gcol] = hb;
        if (t == S_ - 1) hfinal[(size_t)b * H_ + gcol] = hnew;
      }
    }
    __syncthreads();
    if (tid == 0) {
      __threadfence();
      __hip_atomic_fetch_add(flagB, 1, __ATOMIC_RELEASE, __HIP_MEMORY_SCOPE_AGENT);
      const int target = NSLAB_ * (t + 1);
      while (__hip_atomic_load(flagB, __ATOMIC_ACQUIRE, __HIP_MEMORY_SCOPE_AGENT) < target)
        __builtin_amdgcn_s_sleep(2);
    }
    __syncthreads();
  }
}

// ---------------------------------------------------------------- launch
extern "C" void kernel_launch(void* const* d_in, const int* in_sizes, int n_in,
                              void* d_out, int out_size, void* d_ws,
                              size_t ws_size, hipStream_t stream) {
  const float* input = (const float*)d_in[0];
  const float* hs = (const float*)d_in[1];
  const float* W_in[2][3] = {
      {(const float*)d_in[2], (const float*)d_in[5], (const float*)d_in[8]},
      {(const float*)d_in[11], (const float*)d_in[14], (const float*)d_in[17]}};
  const float* W_h[2][3] = {
      {(const float*)d_in[3], (const float*)d_in[6], (const float*)d_in[9]},
      {(const float*)d_in[12], (const float*)d_in[15], (const float*)d_in[18]}};
  const float* bias[2][3] = {
      {(const float*)d_in[4], (const float*)d_in[7], (const float*)d_in[10]},
      {(const float*)d_in[13], (const float*)d_in[16], (const float*)d_in[19]}};
  const float* Wo = (const float*)d_in[20];
  const float* bo = (const float*)d_in[21];
  float* out = (float*)d_out;

  // ---------------- workspace layout (peak ~207.4 MB) ----------------
  // xproj:   [3][BS][H] bf16 (201.3 MB). The z-gate slice doubles as the
  //          layer-1 output sequence (seq2): z[b][t] is consumed in phase A
  //          of step t, h[b][t] written in phase B of the same step.
  // inbf:    bf16 input cast   -> lives in d_out y-region (dead before
  //          h1seq is written)
  // h1seq:   layer-0 output    -> lives in d_out y-region (dead before the
  //          final out-proj GEMM overwrites y)
  char* ws = (char*)d_ws;
  u16* xproj   = (u16*)(ws + 0);             // 201,326,592 B
  u16* wtin0   = (u16*)(ws + 201326592);     // [1536][256]   786,432 B
  u16* wth0    = (u16*)(ws + 202113024);     // [3][512][512] 1,572,864 B
  u16* wtin1   = (u16*)(ws + 203685888);     // [1536][512]   1,572,864 B
  u16* wth1    = (u16*)(ws + 205258752);     // [3][512][512] 1,572,864 B
  u16* wot     = (u16*)(ws + 206831616);     // [256][512]    262,144 B
  u16* hbuf    = (u16*)(ws + 207093760);     // [64][512] bf16
  u16* hrbuf   = (u16*)(ws + 207159296);     // [64][512] bf16
  float* hbuf32 = (float*)(ws + 207224832);  // [64][512] f32
  int* flags   = (int*)(ws + 207355904);     // 8 ints used

  u16* inbf  = (u16*)d_out;                  // 33.5 MB in y-region
  u16* h1seq = (u16*)d_out;                  // 67.1 MB in y-region
  u16* seq2  = xproj;                        // aliases z-gate slice

  // 1. cast input to bf16 (into d_out y-region scratch)
  cast_input_kernel<<<2048, 256, 0, stream>>>(input, inbf, BS_ * IN_ / 4);

  // 2. pack all weights (transpose + cast)
  for (int l = 0; l < 2; ++l) {
    int K = (l == 0) ? IN_ : H_;
    u16* win = (l == 0) ? wtin0 : wtin1;
    u16* wh = (l == 0) ? wth0 : wth1;
    for (int g = 0; g < 3; ++g) {
      pack_transpose_kernel<<<256, 256, 0, stream>>>(W_in[l][g],
                                                     win + (size_t)g * H_ * K, K, H_);
      pack_transpose_kernel<<<256, 256, 0, stream>>>(W_h[l][g],
                                                     wh + (size_t)g * H_ * H_, H_, H_);
    }
  }
  pack_transpose_kernel<<<256, 256, 0, stream>>>(Wo, wot, H_, OUT_);

  const size_t ysz = (size_t)BS_ * OUT_;

  for (int l = 0; l < 2; ++l) {
    const u16* Ain = (l == 0) ? inbf : h1seq;
    int K = (l == 0) ? IN_ : H_;
    // input projections for all timesteps: [BS] x [1536]
    gemm_kernel<<<dim3(24, 1024), 256, 0, stream>>>(
        Ain, (l == 0) ? wtin0 : wtin1, 1536, K, xproj, nullptr, nullptr, 0);

    init_layer_kernel<<<128, 256, 0, stream>>>(hs, hbuf, hbuf32, l, flags);

    u16* seqo = (l == 0) ? h1seq : seq2;
    float* hfin = out + ysz + (size_t)l * B_ * H_;
    const u16* wh = (l == 0) ? wth0 : wth1;
    gru_scan_kernel<<<dim3(NGRP_ * NSLAB_), dim3(256), 0, stream>>>(
        xproj, wh, bias[l][0], bias[l][1], bias[l][2], hbuf, hbuf32, hrbuf,
        seqo, hfin, flags);
  }

  // 3. output projection: y = seq2 @ Wo + bo  (f32 out; overwrites h1seq,
  //    which is dead by now)
  gemm_kernel<<<dim3(4, 1024), 256, 0, stream>>>(seq2, wot, OUT_, H_, nullptr,
                                                 out, bo, 1);
}

// Round 3
// 15337.842 us; speedup vs baseline: 1.7238x; 1.7238x over previous
//
#include <hip/hip_runtime.h>
#include <stdint.h>

typedef unsigned short u16;
typedef short v8s __attribute__((ext_vector_type(8)));
typedef float v4f __attribute__((ext_vector_type(4)));

#define B_ 64
#define S_ 1024
#define IN_ 256
#define H_ 512
#define OUT_ 256
#define BS_ (B_ * S_)                 // 65536
#define GS_ ((size_t)BS_ * H_)        // elems per gate buffer
#define NSLAB_ 16
#define NGRP_ 4
#define HP_ (H_ + 8)                  // padded LDS row (u16 elems)

static __device__ __forceinline__ u16 f2bf(float f) {
  uint32_t u = __float_as_uint(f);
  u += 0x7FFFu + ((u >> 16) & 1u);   // round-to-nearest-even
  return (u16)(u >> 16);
}
static __device__ __forceinline__ float bf2f(u16 h) {
  return __uint_as_float(((uint32_t)h) << 16);
}
static __device__ __forceinline__ v4f mfma16(v8s a, v8s b, v4f c) {
  return __builtin_amdgcn_mfma_f32_16x16x32_bf16(a, b, c, 0, 0, 0);
}
// Coherent (agent-scope, relaxed) accesses: served at the coherence point,
// bypassing potentially-stale L1/L2 copies; no buffer_inv / wbl2 emitted.
static __device__ __forceinline__ uint64_t cload64(const uint64_t* p) {
  return __hip_atomic_load(p, __ATOMIC_RELAXED, __HIP_MEMORY_SCOPE_AGENT);
}
static __device__ __forceinline__ void cstore64(uint64_t* p, uint64_t v) {
  __hip_atomic_store(p, v, __ATOMIC_RELAXED, __HIP_MEMORY_SCOPE_AGENT);
}

// ---------------------------------------------------------------- utilities
__global__ void cast_input_kernel(const float* __restrict__ src,
                                  u16* __restrict__ dst, int n4) {
  int i = blockIdx.x * blockDim.x + threadIdx.x;
  int stride = gridDim.x * blockDim.x;
  for (; i < n4; i += stride) {
    float4 v = ((const float4*)src)[i];
    uint32_t lo = (uint32_t)f2bf(v.x) | ((uint32_t)f2bf(v.y) << 16);
    uint32_t hi = (uint32_t)f2bf(v.z) | ((uint32_t)f2bf(v.w) << 16);
    ((uint2*)dst)[i] = make_uint2(lo, hi);
  }
}

// dst[n*K + k] = bf16(src[k*N + n])   (transpose + cast)
__global__ void pack_transpose_kernel(const float* __restrict__ src,
                                      u16* __restrict__ dst, int K, int N) {
  int i = blockIdx.x * blockDim.x + threadIdx.x;
  int total = K * N;
  int stride = gridDim.x * blockDim.x;
  for (; i < total; i += stride) {
    int n = i / K, k = i - n * K;
    dst[i] = f2bf(src[(size_t)k * N + n]);
  }
}

__global__ void zero_flags_kernel(int* __restrict__ flags) {
  if (threadIdx.x < 16) flags[threadIdx.x] = 0;
}

// ---------------------------------------------------------------- GEMM
// C[M x N] = A[M x K] * Bt[N x K]^T ; 64x64 block tile, 4 waves of 32x32.
// mode 0: bf16 out split into 3 gate buffers of [BS_][H_] (N = 1536)
// mode 1: f32 out with bias (N = OUT_)
__global__ void __launch_bounds__(256) gemm_kernel(
    const u16* __restrict__ A, const u16* __restrict__ Bt, int N, int K,
    u16* __restrict__ outb, float* __restrict__ outf,
    const float* __restrict__ bias, int mode) {
  const int bn = blockIdx.x * 64;
  const int bm = blockIdx.y * 64;
  const int w = threadIdx.x >> 6;
  const int lane = threadIdx.x & 63;
  const int wm = (w >> 1) * 32, wn = (w & 1) * 32;
  const int fr = lane & 15;
  const int kb = (lane >> 4) * 8;
  v4f acc00 = {0,0,0,0}, acc01 = {0,0,0,0}, acc10 = {0,0,0,0}, acc11 = {0,0,0,0};
  const u16* a0p = A + (size_t)(bm + wm + fr) * K + kb;
  const u16* a1p = a0p + (size_t)16 * K;
  const u16* b0p = Bt + (size_t)(bn + wn + fr) * K + kb;
  const u16* b1p = b0p + (size_t)16 * K;
  for (int kk = 0; kk < K; kk += 32) {
    v8s a0 = *(const v8s*)(a0p + kk);
    v8s a1 = *(const v8s*)(a1p + kk);
    v8s b0 = *(const v8s*)(b0p + kk);
    v8s b1 = *(const v8s*)(b1p + kk);
    acc00 = mfma16(a0, b0, acc00);
    acc01 = mfma16(a0, b1, acc01);
    acc10 = mfma16(a1, b0, acc10);
    acc11 = mfma16(a1, b1, acc11);
  }
  v4f accs[2][2] = {{acc00, acc01}, {acc10, acc11}};
  const int rb = (lane >> 4) * 4;
#pragma unroll
  for (int mi = 0; mi < 2; ++mi)
#pragma unroll
    for (int ni = 0; ni < 2; ++ni)
#pragma unroll
      for (int j = 0; j < 4; ++j) {
        int row = bm + wm + mi * 16 + rb + j;
        int col = bn + wn + ni * 16 + fr;
        float v = accs[mi][ni][j];
        if (mode == 0) {
          int gate = col >> 9, c = col & (H_ - 1);
          outb[(size_t)gate * GS_ + (size_t)row * H_ + c] = f2bf(v);
        } else {
          outf[(size_t)row * N + col] = v + bias[col];
        }
      }
}

// ---------------------------------------------------------------- GRU scan
// 64 WGs = 4 batch-groups (16 rows) x 16 column-slabs (32 cols).
// Recurrent weight slabs live in LDS for all 1024 steps. h / hr are
// exchanged through RELAXED agent-scope atomics only (no fences, no L2
// inv/wb): writer stores coherently, waits vmcnt(0), bumps a relaxed flag;
// readers poll the flag relaxed and stage the peer block into LDS with
// coherent loads.
// NOTE: xproj and seqout may alias for layer 1 (h overwrites the consumed
// z-projection slot of the same step) -> no __restrict__ on them.
__global__ void __launch_bounds__(256, 1) gru_scan_kernel(
    const u16* xproj,                // [3][BS_][H_] bf16 (z,r,g)
    const u16* __restrict__ Wht,     // [3][H_][H_] bf16, Wt[g][n][k] = W[k][n]
    const float* __restrict__ bz, const float* __restrict__ br,
    const float* __restrict__ bg,
    const float* __restrict__ hs,    // [B_][2][H_] f32 initial state
    int layer,
    u16* hbuf,                       // [NGRP_*16][H_] bf16 exchange
    u16* hrbuf,                      // [NGRP_*16][H_] bf16 exchange
    u16* seqout,                     // [B_][S_][H_] bf16
    float* __restrict__ hfinal,      // [B_][H_] f32 (d_out tail slice)
    int* __restrict__ flags) {
  __shared__ __align__(16) u16 ldsW[3][32][HP_];  // 99,840 B
  __shared__ __align__(16) u16 ldsX[16][HP_];     // 16,640 B (h / hr staging)
  __shared__ float h32[16][32];                   //  2,048 B (own-col f32 h)
  const int grp = blockIdx.x & (NGRP_ - 1);
  const int slab = blockIdx.x >> 2;
  const int j0 = slab * 32;
  const int tid = threadIdx.x;
  const int gb = grp * 16;          // batch row base of this group

  // stage weight slabs (once)
  for (int idx = tid; idx < 3 * 32 * 64; idx += 256) {
    int gate = idx >> 11;
    int rem = idx & 2047;
    int cl = rem >> 6;
    int kc = (rem & 63) * 8;
    *(v8s*)&ldsW[gate][cl][kc] =
        *(const v8s*)(Wht + ((size_t)gate * H_ + (j0 + cl)) * H_ + kc);
  }
  // h0 init: bf16 full block + f32 own columns
  for (int i = tid; i < 16 * H_; i += 256) {
    int row = i >> 9, col = i & (H_ - 1);
    ldsX[row][col] = f2bf(hs[((size_t)(gb + row) * 2 + layer) * H_ + col]);
  }
  for (int i = tid; i < 16 * 32; i += 256) {
    int row = i >> 5, cl = i & 31;
    h32[row][cl] = hs[((size_t)(gb + row) * 2 + layer) * H_ + j0 + cl];
  }
  __syncthreads();

  const int w = tid >> 6, lane = tid & 63;
  const int fr = lane & 15;
  const int kb = (lane >> 4) * 8;
  const int rb = (lane >> 4) * 4;
  const int nt = w & 1;             // N-tile within slab
  const int gateA = w >> 1;         // waves 0,1 -> z ; waves 2,3 -> r
  const int colL = nt * 16 + fr;
  const int gcol = j0 + colL;
  const float biasA = (gateA == 0) ? bz[gcol] : br[gcol];
  const float biasG = bg[gcol];
  int* flagA = flags + grp;
  int* flagB = flags + NGRP_ + grp;

  u16* hbuf_g = hbuf + (size_t)gb * H_;
  u16* hrbuf_g = hrbuf + (size_t)gb * H_;
  const u16* xA = xproj + (size_t)gateA * GS_;
  const u16* xG = xproj + (size_t)2 * GS_;
  const u16* wA = &ldsW[gateA][colL][0];
  const u16* wG = &ldsW[2][colL][0];

  float zv0 = 0.f, zv1 = 0.f, zv2 = 0.f, zv3 = 0.f;

  for (int t = 0; t < S_; ++t) {
    if (t > 0) {
      // stage h(t-1) block: 2048 qwords, coherent
      uint64_t vq[8];
#pragma unroll
      for (int i = 0; i < 8; ++i)
        vq[i] = cload64((const uint64_t*)hbuf_g + i * 256 + tid);
#pragma unroll
      for (int i = 0; i < 8; ++i) {
        int d = i * 256 + tid;
        *(uint64_t*)&ldsX[d >> 7][(d & 127) * 4] = vq[i];
      }
      __syncthreads();
    }

    // ---------- phase A: z (waves 0,1) and r -> hr (waves 2,3) ----------
    v4f acc0 = {0,0,0,0}, acc1 = {0,0,0,0};
#pragma unroll
    for (int kk = 0; kk < 8; ++kk) {
      v8s a0 = *(const v8s*)&ldsX[fr][kk * 32 + kb];
      v8s b0 = *(const v8s*)(wA + kk * 32 + kb);
      acc0 = mfma16(a0, b0, acc0);
      v8s a1 = *(const v8s*)&ldsX[fr][256 + kk * 32 + kb];
      v8s b1 = *(const v8s*)(wA + 256 + kk * 32 + kb);
      acc1 = mfma16(a1, b1, acc1);
    }
    float pre[4];
#pragma unroll
    for (int j = 0; j < 4; ++j) {
      int b = gb + rb + j;
      float x = bf2f(xA[((size_t)b * S_ + t) * H_ + gcol]);
      float s = acc0[j] + acc1[j] + x + biasA;
      pre[j] = 1.0f / (1.0f + __expf(-s));
    }
    if (gateA == 0) {
      zv0 = pre[0]; zv1 = pre[1]; zv2 = pre[2]; zv3 = pre[3];
    } else {
#pragma unroll
      for (int j = 0; j < 4; ++j) {
        float v = pre[j] * h32[rb + j][colL];
        float o1 = __shfl_xor(v, 1);
        uint32_t c0 = f2bf(v), c1 = f2bf(o1);
        uint32_t pk = (fr & 1) ? (c1 | (c0 << 16)) : (c0 | (c1 << 16));
        uint32_t pk2 = __shfl_xor(pk, 2);
        if ((fr & 3) == 0) {
          uint64_t q = (uint64_t)pk | ((uint64_t)pk2 << 32);
          cstore64((uint64_t*)&hrbuf_g[(size_t)(rb + j) * H_ + gcol], q);
        }
      }
    }
    // barrier A
    asm volatile("s_waitcnt vmcnt(0)" ::: "memory");
    __syncthreads();
    if (tid == 0) {
      __hip_atomic_fetch_add(flagA, 1, __ATOMIC_RELAXED, __HIP_MEMORY_SCOPE_AGENT);
      const int target = NSLAB_ * (t + 1);
      while (__hip_atomic_load(flagA, __ATOMIC_RELAXED, __HIP_MEMORY_SCOPE_AGENT) < target)
        __builtin_amdgcn_s_sleep(1);
    }
    __syncthreads();

    // stage hr block
    {
      uint64_t vq[8];
#pragma unroll
      for (int i = 0; i < 8; ++i)
        vq[i] = cload64((const uint64_t*)hrbuf_g + i * 256 + tid);
#pragma unroll
      for (int i = 0; i < 8; ++i) {
        int d = i * 256 + tid;
        *(uint64_t*)&ldsX[d >> 7][(d & 127) * 4] = vq[i];
      }
      __syncthreads();
    }

    // ---------- phase B: g (waves 0,1), h update ----------
    if (w < 2) {
      v4f g0 = {0,0,0,0}, g1 = {0,0,0,0};
#pragma unroll
      for (int kk = 0; kk < 8; ++kk) {
        v8s a0 = *(const v8s*)&ldsX[fr][kk * 32 + kb];
        v8s b0 = *(const v8s*)(wG + kk * 32 + kb);
        g0 = mfma16(a0, b0, g0);
        v8s a1 = *(const v8s*)&ldsX[fr][256 + kk * 32 + kb];
        v8s b1 = *(const v8s*)(wG + 256 + kk * 32 + kb);
        g1 = mfma16(a1, b1, g1);
      }
      float zv[4] = {zv0, zv1, zv2, zv3};
#pragma unroll
      for (int j = 0; j < 4; ++j) {
        int b = gb + rb + j;
        float xg = bf2f(xG[((size_t)b * S_ + t) * H_ + gcol]);
        float gval = tanhf(g0[j] + g1[j] + xg + biasG);
        float hold = h32[rb + j][colL];
        float hnew = zv[j] * hold + (1.0f - zv[j]) * gval;
        h32[rb + j][colL] = hnew;
        float o1 = __shfl_xor(hnew, 1);
        uint32_t c0 = f2bf(hnew), c1 = f2bf(o1);
        uint32_t pk = (fr & 1) ? (c1 | (c0 << 16)) : (c0 | (c1 << 16));
        uint32_t pk2 = __shfl_xor(pk, 2);
        if ((fr & 3) == 0) {
          uint64_t q = (uint64_t)pk | ((uint64_t)pk2 << 32);
          cstore64((uint64_t*)&hbuf_g[(size_t)(rb + j) * H_ + gcol], q);
          *(uint64_t*)&seqout[((size_t)b * S_ + t) * H_ + gcol] = q;
        }
        if (t == S_ - 1) hfinal[(size_t)b * H_ + gcol] = hnew;
      }
    }
    // barrier B
    asm volatile("s_waitcnt vmcnt(0)" ::: "memory");
    __syncthreads();
    if (tid == 0) {
      __hip_atomic_fetch_add(flagB, 1, __ATOMIC_RELAXED, __HIP_MEMORY_SCOPE_AGENT);
      const int target = NSLAB_ * (t + 1);
      while (__hip_atomic_load(flagB, __ATOMIC_RELAXED, __HIP_MEMORY_SCOPE_AGENT) < target)
        __builtin_amdgcn_s_sleep(1);
    }
    __syncthreads();
  }
}

// ---------------------------------------------------------------- launch
extern "C" void kernel_launch(void* const* d_in, const int* in_sizes, int n_in,
                              void* d_out, int out_size, void* d_ws,
                              size_t ws_size, hipStream_t stream) {
  const float* input = (const float*)d_in[0];
  const float* hs = (const float*)d_in[1];
  const float* W_in[2][3] = {
      {(const float*)d_in[2], (const float*)d_in[5], (const float*)d_in[8]},
      {(const float*)d_in[11], (const float*)d_in[14], (const float*)d_in[17]}};
  const float* W_h[2][3] = {
      {(const float*)d_in[3], (const float*)d_in[6], (const float*)d_in[9]},
      {(const float*)d_in[12], (const float*)d_in[15], (const float*)d_in[18]}};
  const float* bias[2][3] = {
      {(const float*)d_in[4], (const float*)d_in[7], (const float*)d_in[10]},
      {(const float*)d_in[13], (const float*)d_in[16], (const float*)d_in[19]}};
  const float* Wo = (const float*)d_in[20];
  const float* bo = (const float*)d_in[21];
  float* out = (float*)d_out;

  // ---------------- workspace layout (peak ~207.4 MB) ----------------
  char* ws = (char*)d_ws;
  u16* xproj   = (u16*)(ws + 0);             // 201,326,592 B
  u16* wtin0   = (u16*)(ws + 201326592);     // [1536][256]
  u16* wth0    = (u16*)(ws + 202113024);     // [3][512][512]
  u16* wtin1   = (u16*)(ws + 203685888);     // [1536][512]
  u16* wth1    = (u16*)(ws + 205258752);     // [3][512][512]
  u16* wot     = (u16*)(ws + 206831616);     // [256][512]
  u16* hbuf    = (u16*)(ws + 207093760);     // [64][512] bf16 exchange
  u16* hrbuf   = (u16*)(ws + 207159296);     // [64][512] bf16 exchange
  int* flags   = (int*)(ws + 207355904);     // 16 ints

  u16* inbf  = (u16*)d_out;                  // 33.5 MB in d_out y-region
  u16* h1seq = (u16*)d_out;                  // 67.1 MB in d_out y-region
  u16* seq2  = xproj;                        // aliases z-gate slice

  // 1. cast input to bf16 (into d_out y-region scratch)
  cast_input_kernel<<<2048, 256, 0, stream>>>(input, inbf, BS_ * IN_ / 4);

  // 2. pack all weights (transpose + cast)
  for (int l = 0; l < 2; ++l) {
    int K = (l == 0) ? IN_ : H_;
    u16* win = (l == 0) ? wtin0 : wtin1;
    u16* wh = (l == 0) ? wth0 : wth1;
    for (int g = 0; g < 3; ++g) {
      pack_transpose_kernel<<<256, 256, 0, stream>>>(W_in[l][g],
                                                     win + (size_t)g * H_ * K, K, H_);
      pack_transpose_kernel<<<256, 256, 0, stream>>>(W_h[l][g],
                                                     wh + (size_t)g * H_ * H_, H_, H_);
    }
  }
  pack_transpose_kernel<<<256, 256, 0, stream>>>(Wo, wot, H_, OUT_);

  const size_t ysz = (size_t)BS_ * OUT_;

  for (int l = 0; l < 2; ++l) {
    const u16* Ain = (l == 0) ? inbf : h1seq;
    int K = (l == 0) ? IN_ : H_;
    gemm_kernel<<<dim3(24, 1024), 256, 0, stream>>>(
        Ain, (l == 0) ? wtin0 : wtin1, 1536, K, xproj, nullptr, nullptr, 0);

    zero_flags_kernel<<<1, 64, 0, stream>>>(flags);

    u16* seqo = (l == 0) ? h1seq : seq2;
    float* hfin = out + ysz + (size_t)l * B_ * H_;
    const u16* wh = (l == 0) ? wth0 : wth1;
    gru_scan_kernel<<<dim3(NGRP_ * NSLAB_), dim3(256), 0, stream>>>(
        xproj, wh, bias[l][0], bias[l][1], bias[l][2], hs, l, hbuf, hrbuf,
        seqo, hfin, flags);
  }

  // 3. output projection: y = seq2 @ Wo + bo (overwrites h1seq, dead by now)
  gemm_kernel<<<dim3(4, 1024), 256, 0, stream>>>(seq2, wot, OUT_, H_, nullptr,
                                                 out, bo, 1);
}